// Round 5
// baseline (166.780 us; speedup 1.0000x reference)
//
#include <hip/hip_runtime.h>
#include <hip/hip_bf16.h>
#include <stdint.h>

typedef unsigned short u16;
typedef __attribute__((ext_vector_type(8))) short bf16x8;
typedef __attribute__((ext_vector_type(4))) float f32x4;
typedef __attribute__((ext_vector_type(2))) float f32x2;
typedef __attribute__((ext_vector_type(4))) unsigned int u32x4;
typedef __attribute__((ext_vector_type(2))) unsigned int u32x2;

#define NTOK 4096
#define NT32 32   // 4096 / 128 t2-tiles

#if __has_builtin(__builtin_amdgcn_exp2f)
#define EXP2F __builtin_amdgcn_exp2f
#else
#define EXP2F exp2f
#endif

__device__ __forceinline__ f32x4 MFMA(bf16x8 a, bf16x8 b, f32x4 c) {
    return __builtin_amdgcn_mfma_f32_16x16x32_bf16(a, b, c, 0, 0, 0);
}

// packed f32->bf16 (D.lo = bf16(a), D.hi = bf16(b))
__device__ __forceinline__ uint32_t pk_bf16(float a, float b) {
    uint32_t d;
    asm("v_cvt_pk_bf16_f32 %0, %1, %2" : "=v"(d) : "v"(a), "v"(b));
    return d;
}

// truncation hi/lo split of 8 floats into two bf16x8 fragments
__device__ __forceinline__ void hilo_pack8(const float* v, bf16x8* h, bf16x8* l) {
    union { uint32_t u[4]; bf16x8 b; } H, L;
#pragma unroll
    for (int m = 0; m < 4; ++m) {
        const uint32_t ua = __float_as_uint(v[2*m]);
        const uint32_t ub = __float_as_uint(v[2*m+1]);
        const float la = v[2*m]   - __uint_as_float(ua & 0xffff0000u);
        const float lb = v[2*m+1] - __uint_as_float(ub & 0xffff0000u);
        H.u[m] = (ua >> 16) | (ub & 0xffff0000u);
        L.u[m] = (__float_as_uint(la) >> 16) | (__float_as_uint(lb) & 0xffff0000u);
    }
    *h = H.b; *l = L.b;
}

// ---------------------------------------------------------------------------
// k_qkv: QKV projection via MFMA (w,x hi/lo 3-term), then repack through LDS.
// (unchanged from round 4)
// ---------------------------------------------------------------------------
__global__ __launch_bounds__(256) void k_qkv(
    const float* __restrict__ x, const float* __restrict__ wqkv, const float* __restrict__ bqkv,
    u16* __restrict__ Qp, u16* __restrict__ Kp, u16* __restrict__ Vp)
{
    __shared__ float qt_lds[64 * 194];
    const int blk = blockIdx.x;
    const int b   = blk >> 6;
    const int tb  = (blk & 63) << 6;
    const int tid = threadIdx.x;
    const int lane = tid & 63;
    const int wv  = __builtin_amdgcn_readfirstlane(tid >> 6);
    const int r   = lane & 15;
    const int g   = lane >> 4;
    const int o0  = wv * 48;

    bf16x8 wh[3][2], wl[3][2];
#pragma unroll
    for (int oi = 0; oi < 3; ++oi)
#pragma unroll
        for (int ks = 0; ks < 2; ++ks) {
            const float* wp = wqkv + (size_t)(o0 + oi*16 + r) * 64 + ks*32 + g*8;
            float wv8[8];
            *(f32x4*)(wv8)     = *(const f32x4*)(wp);
            *(f32x4*)(wv8 + 4) = *(const f32x4*)(wp + 4);
            hilo_pack8(wv8, &wh[oi][ks], &wl[oi][ks]);
        }

    f32x4 acc[3][4];
#pragma unroll
    for (int oi = 0; oi < 3; ++oi)
#pragma unroll
        for (int tt = 0; tt < 4; ++tt) acc[oi][tt] = 0.f;

#pragma unroll
    for (int tt = 0; tt < 4; ++tt) {
        bf16x8 xh[2], xl[2];
#pragma unroll
        for (int ks = 0; ks < 2; ++ks) {
            float xv[8];
#pragma unroll
            for (int j = 0; j < 8; ++j)
                xv[j] = x[(size_t)(b*64 + ks*32 + g*8 + j) * NTOK + tb + tt*16 + r];
            hilo_pack8(xv, &xh[ks], &xl[ks]);
        }
#pragma unroll
        for (int oi = 0; oi < 3; ++oi) {
            f32x4 a = acc[oi][tt];
            a = MFMA(wh[oi][0], xh[0], a);
            a = MFMA(wh[oi][1], xh[1], a);
            a = MFMA(wl[oi][0], xh[0], a);
            a = MFMA(wl[oi][1], xh[1], a);
            a = MFMA(wh[oi][0], xl[0], a);
            a = MFMA(wh[oi][1], xl[1], a);
            acc[oi][tt] = a;
        }
    }

#pragma unroll
    for (int oi = 0; oi < 3; ++oi)
#pragma unroll
        for (int tt = 0; tt < 4; ++tt)
#pragma unroll
            for (int i = 0; i < 4; ++i)
                qt_lds[(tt*16 + r) * 194 + o0 + oi*16 + g*4 + i] = acc[oi][tt][i];
    __syncthreads();

    const float SC = 0.18033688011112042f;  // (1/8) * log2(e)

    {
        const int t = tid >> 2, c0 = (tid & 3) * 16;
        float v[16], bq[16];
#pragma unroll
        for (int m = 0; m < 8; ++m)
            *(f32x2*)(v + 2*m) = *(const f32x2*)&qt_lds[t*194 + c0 + 2*m];
#pragma unroll
        for (int m = 0; m < 4; ++m)
            *(f32x4*)(bq + 4*m) = *(const f32x4*)(bqkv + c0 + 4*m);
        u32x4 P0, P1;
#pragma unroll
        for (int m = 0; m < 4; ++m) {
            P0[m] = pk_bf16((v[2*m]   + bq[2*m]  ) * SC, (v[2*m+1] + bq[2*m+1]) * SC);
            P1[m] = pk_bf16((v[8+2*m] + bq[8+2*m]) * SC, (v[9+2*m] + bq[9+2*m]) * SC);
        }
        size_t base = ((size_t)(b * NTOK + tb + t)) * 64 + c0;
        *(u32x4*)(Qp + base)     = P0;
        *(u32x4*)(Qp + base + 8) = P1;
    }

#pragma unroll
    for (int uu = 0; uu < 2; ++uu) {
        const int u  = tid * 2 + uu;
        const int t  = u >> 3;
        const int ks = (u >> 2) & 1;
        const int gk = u & 3;
        const int cb0 = 64 + ks*32 + gk*8;
        float v[8];
#pragma unroll
        for (int m = 0; m < 4; ++m)
            *(f32x2*)(v + 2*m) = *(const f32x2*)&qt_lds[t*194 + cb0 + 2*m];
        u32x4 P;
#pragma unroll
        for (int m = 0; m < 4; ++m)
            P[m] = pk_bf16(v[2*m] + bqkv[cb0 + 2*m], v[2*m+1] + bqkv[cb0 + 2*m+1]);
        const int tg = tb + t;
        size_t kbase = (size_t)b * 262144 + ((size_t)(tg >> 4) * 2 + ks) * 512 + gk*128 + (t & 15) * 8;
        *(u32x4*)(Kp + kbase) = P;
    }

    {
        const int cb = (tid >> 4) & 3;
        const int r2 = tid & 15;
        const float bv = bqkv[128 + cb*16 + r2];
        const int T = (blk & 63) >> 1;
        const int halfb = blk & 1;
#pragma unroll
        for (int m = 0; m < 4; ++m) {
            const int tq = m * 4 + (tid >> 6);
            float v[4];
#pragma unroll
            for (int jj = 0; jj < 4; ++jj)
                v[jj] = qt_lds[(tq*4 + jj)*194 + 128 + cb*16 + r2] + bv;
            const int t = tq * 4;
            const int wtr = halfb*2 + (t >> 5);
            const int sti = (t >> 4) & 1;
            const int g2  = (t >> 2) & 3;
            u32x2 W;
            W[0] = pk_bf16(v[0], v[1]);
            W[1] = pk_bf16(v[2], v[3]);
            size_t vbase = (size_t)b * 262144 +
                           (((size_t)T * 4 + wtr) * 4 + cb) * 512 + (g2*16 + r2) * 8 + sti * 4;
            *(u32x2*)(Vp + vbase) = W;
        }
    }
}

// ---------------------------------------------------------------------------
// k_attn: flash attention, register-only barrier-free main loop, 512-thread
// blocks = 8 waves = 2 Q-groups (32 rows) x 4 t2-slices (32 of 128 tile).
// 4 waves/SIMD for latency hiding; K double-buffered via unroll-2 A/B regs.
// 8-way split-softmax merge + fused out-projection + residual in epilogue.
// ---------------------------------------------------------------------------
__global__ __launch_bounds__(512, 4) void k_attn(
    const u16* __restrict__ Qp, const u16* __restrict__ Kp, const u16* __restrict__ Vp,
    const float* __restrict__ wout, const float* __restrict__ bout,
    const float* __restrict__ x, float* __restrict__ out)
{
    __shared__ float marr[8][2][16];
    __shared__ float larr[8][2][16];
    __shared__ float otbuf[2][64 * 67];
    const int hw  = blockIdx.x;
    const int b   = hw & 7;        // batch -> XCD pinning
    const int qt  = hw >> 3;       // 0..63
    const int tid = threadIdx.x;
    const int lane = tid & 63;
    const int wv  = tid >> 6;      // 0..7
    const int wq  = wv >> 2;       // Q-half (32 rows)
    const int wt2 = wv & 3;        // t2-slice (32 of 128)
    const int r   = lane & 15;
    const int g   = lane >> 4;

    // Q fragments (B operand), rows t1 = qt*64 + wq*32 + rt*16 + r
    bf16x8 qh[2][2];
#pragma unroll
    for (int rt = 0; rt < 2; ++rt) {
        const int t1 = qt * 64 + wq * 32 + rt * 16 + r;
        const size_t qoff = ((size_t)(b * NTOK + t1)) * 64 + g * 8;
        qh[rt][0] = *(const bf16x8*)(Qp + qoff);
        qh[rt][1] = *(const bf16x8*)(Qp + qoff + 32);
    }

    const u16* Kb = Kp + (size_t)b * 262144;
    const u16* Vb = Vp + (size_t)b * 262144;

    f32x4 oacc[2][4];
#pragma unroll
    for (int rt = 0; rt < 2; ++rt)
#pragma unroll
        for (int cb = 0; cb < 4; ++cb) oacc[rt][cb] = 0.f;
    float mrun[2] = {-1e30f, -1e30f};
    float lpart[2] = {0.f, 0.f};

    bf16x8 kA[2][2], kB[2][2];
#pragma unroll
    for (int sti = 0; sti < 2; ++sti)
#pragma unroll
        for (int ks = 0; ks < 2; ++ks) {
            kA[sti][ks] = *(const bf16x8*)(Kb + ((((size_t)0*8 + wt2*2 + sti) * 2 + ks) * 64 + lane) * 8);
            kB[sti][ks] = *(const bf16x8*)(Kb + ((((size_t)1*8 + wt2*2 + sti) * 2 + ks) * 64 + lane) * 8);
        }

    auto body = [&](bf16x8 (&kb)[2][2], int T, int Tp) {
        // V fragments for this tile
        bf16x8 vf[4];
#pragma unroll
        for (int cb = 0; cb < 4; ++cb)
            vf[cb] = *(const bf16x8*)(Vb + ((((size_t)T * 4 + wt2) * 4 + cb) * 64 + lane) * 8);

        // QK^T
        f32x4 s[2][2];
        __builtin_amdgcn_s_setprio(1);
#pragma unroll
        for (int rt = 0; rt < 2; ++rt)
#pragma unroll
            for (int sti = 0; sti < 2; ++sti) {
                f32x4 a = 0.f;
                a = MFMA(kb[sti][0], qh[rt][0], a);
                a = MFMA(kb[sti][1], qh[rt][1], a);
                s[rt][sti] = a;
            }
        __builtin_amdgcn_s_setprio(0);

        // prefetch K for tile Tp into the buffer just consumed
        if (Tp < NT32) {
#pragma unroll
            for (int sti = 0; sti < 2; ++sti)
#pragma unroll
                for (int ks = 0; ks < 2; ++ks)
                    kb[sti][ks] = *(const bf16x8*)(Kb + ((((size_t)Tp*8 + wt2*2 + sti) * 2 + ks) * 64 + lane) * 8);
        }

        // online softmax, deferred rescale (thr = 8 log2 units)
        float m8[2];
#pragma unroll
        for (int rt = 0; rt < 2; ++rt) {
            float a = fmaxf(fmaxf(s[rt][0][0], s[rt][0][1]), fmaxf(s[rt][0][2], s[rt][0][3]));
            float c = fmaxf(fmaxf(s[rt][1][0], s[rt][1][1]), fmaxf(s[rt][1][2], s[rt][1][3]));
            m8[rt] = fmaxf(a, c);
        }
        const bool need = (m8[0] > mrun[0] + 8.f) || (m8[1] > mrun[1] + 8.f);
        if (__any(need)) {
#pragma unroll
            for (int rt = 0; rt < 2; ++rt) {
                float mr = fmaxf(m8[rt], __shfl_xor(m8[rt], 16));
                mr = fmaxf(mr, __shfl_xor(mr, 32));
                const float mnew = fmaxf(mrun[rt], mr);
                const float corr = EXP2F(mrun[rt] - mnew);
                lpart[rt] *= corr;
                float c4[4];
#pragma unroll
                for (int i = 0; i < 4; ++i) c4[i] = __shfl(corr, g * 4 + i);
#pragma unroll
                for (int cb = 0; cb < 4; ++cb)
#pragma unroll
                    for (int i = 0; i < 4; ++i) oacc[rt][cb][i] *= c4[i];
                mrun[rt] = mnew;
            }
        }

        // P = exp2(S - m), PV
#pragma unroll
        for (int rt = 0; rt < 2; ++rt) {
            float p[8];
            float ls = 0.f;
#pragma unroll
            for (int sti = 0; sti < 2; ++sti)
#pragma unroll
                for (int i = 0; i < 4; ++i) {
                    const float pv = EXP2F(s[rt][sti][i] - mrun[rt]);
                    p[sti*4 + i] = pv; ls += pv;
                }
            lpart[rt] += ls;
            union { uint32_t u[4]; bf16x8 b; } PA;
#pragma unroll
            for (int m = 0; m < 4; ++m) PA.u[m] = pk_bf16(p[2*m], p[2*m+1]);
            __builtin_amdgcn_s_setprio(1);
#pragma unroll
            for (int cb = 0; cb < 4; ++cb)
                oacc[rt][cb] = MFMA(PA.b, vf[cb], oacc[rt][cb]);
            __builtin_amdgcn_s_setprio(0);
        }
    };

    for (int T = 0; T < NT32; T += 2) {
        body(kA, T,     T + 2);
        body(kB, T + 1, T + 3);
    }

    // ---- epilogue: 8-way (4 per Q-group) split-softmax merge ----
    float lsum[2];
#pragma unroll
    for (int rt = 0; rt < 2; ++rt) {
        float v = lpart[rt];
        v += __shfl_xor(v, 16);
        v += __shfl_xor(v, 32);
        lsum[rt] = v;
    }
    if (lane < 16) {
#pragma unroll
        for (int rt = 0; rt < 2; ++rt) {
            marr[wv][rt][lane] = mrun[rt];
            larr[wv][rt][lane] = lsum[rt];
        }
    }
    __syncthreads();

    float w4[2][4];
#pragma unroll
    for (int rt = 0; rt < 2; ++rt) {
        const float m0 = marr[wq*4+0][rt][r], m1 = marr[wq*4+1][rt][r];
        const float m2 = marr[wq*4+2][rt][r], m3 = marr[wq*4+3][rt][r];
        const float mstar = fmaxf(fmaxf(m0, m1), fmaxf(m2, m3));
        const float lstar = larr[wq*4+0][rt][r] * EXP2F(m0 - mstar)
                          + larr[wq*4+1][rt][r] * EXP2F(m1 - mstar)
                          + larr[wq*4+2][rt][r] * EXP2F(m2 - mstar)
                          + larr[wq*4+3][rt][r] * EXP2F(m3 - mstar);
        const float wsc = EXP2F(mrun[rt] - mstar) / lstar;
#pragma unroll
        for (int i = 0; i < 4; ++i) w4[rt][i] = __shfl(wsc, g * 4 + i);
    }

    // accumulate O tile: wt2 0/1 write buf0/buf1, wt2 2/3 add to buf0/buf1
    if (wt2 < 2) {
        float* ob = otbuf[wt2];
#pragma unroll
        for (int rt = 0; rt < 2; ++rt)
#pragma unroll
            for (int cb = 0; cb < 4; ++cb)
#pragma unroll
                for (int i = 0; i < 4; ++i)
                    ob[(wq*32 + rt*16 + g*4 + i)*67 + cb*16 + r] = oacc[rt][cb][i] * w4[rt][i];
    }
    __syncthreads();
    if (wt2 >= 2) {
        float* ob = otbuf[wt2 - 2];
#pragma unroll
        for (int rt = 0; rt < 2; ++rt)
#pragma unroll
            for (int cb = 0; cb < 4; ++cb)
#pragma unroll
                for (int i = 0; i < 4; ++i)
                    ob[(wq*32 + rt*16 + g*4 + i)*67 + cb*16 + r] += oacc[rt][cb][i] * w4[rt][i];
    }
    __syncthreads();

    // ---- fused out-projection + bias + residual ----
    // wave wv: token group tg = wv&3 (rows tg*16 + r), output half oh = wv>>2
    const int tg = wv & 3;
    const int oh = wv >> 2;
    bf16x8 oh_[2], ol_[2];
#pragma unroll
    for (int ks = 0; ks < 2; ++ks) {
        float ov[8];
#pragma unroll
        for (int j = 0; j < 8; ++j) {
            const int idx = (tg*16 + r)*67 + ks*32 + g*8 + j;
            ov[j] = otbuf[0][idx] + otbuf[1][idx];
        }
        hilo_pack8(ov, &oh_[ks], &ol_[ks]);
    }
    f32x4 acc2[2];
#pragma unroll
    for (int ot = 0; ot < 2; ++ot) {
        bf16x8 wh2[2], wl2[2];
#pragma unroll
        for (int ks = 0; ks < 2; ++ks) {
            const float* wp = wout + (size_t)((oh*2 + ot)*16 + r) * 64 + ks*32 + g*8;
            float wv8[8];
            *(f32x4*)(wv8)     = *(const f32x4*)(wp);
            *(f32x4*)(wv8 + 4) = *(const f32x4*)(wp + 4);
            hilo_pack8(wv8, &wh2[ks], &wl2[ks]);
        }
        f32x4 a = 0.f;
        a = MFMA(wh2[0], oh_[0], a);
        a = MFMA(wh2[1], oh_[1], a);
        a = MFMA(wl2[0], oh_[0], a);
        a = MFMA(wl2[1], oh_[1], a);
        a = MFMA(wh2[0], ol_[0], a);
        a = MFMA(wh2[1], ol_[1], a);
        acc2[ot] = a;
    }
#pragma unroll
    for (int ot = 0; ot < 2; ++ot)
#pragma unroll
        for (int i = 0; i < 4; ++i) {
            const int oo = (oh*2 + ot)*16 + g*4 + i;
            const size_t xi = ((size_t)(b*64 + oo)) * NTOK + qt*64 + tg*16 + r;
            out[xi] = acc2[ot][i] + bout[oo] + x[xi];
        }
}

extern "C" void kernel_launch(void* const* d_in, const int* in_sizes, int n_in,
                              void* d_out, int out_size, void* d_ws, size_t ws_size,
                              hipStream_t stream)
{
    (void)in_sizes; (void)n_in; (void)out_size; (void)ws_size;
    const float* x    = (const float*)d_in[0];
    const float* wqkv = (const float*)d_in[1];
    const float* bqkv = (const float*)d_in[2];
    const float* wout = (const float*)d_in[3];
    const float* bout = (const float*)d_in[4];
    float* out = (float*)d_out;

    char* ws = (char*)d_ws;
    const size_t MB = 1024 * 1024;
    u16* Qp = (u16*)(ws);
    u16* Kp = (u16*)(ws + 4 * MB);
    u16* Vp = (u16*)(ws + 8 * MB);

    k_qkv<<<512, 256, 0, stream>>>(x, wqkv, bqkv, Qp, Kp, Vp);
    k_attn<<<512, 512, 0, stream>>>(Qp, Kp, Vp, wout, bout, x, out);
}

// Round 6
// 65.797 us; speedup vs baseline: 2.5348x; 2.5348x over previous
//
#include <hip/hip_runtime.h>
#include <hip/hip_bf16.h>
#include <stdint.h>

typedef unsigned short u16;
typedef __attribute__((ext_vector_type(8))) short bf16x8;
typedef __attribute__((ext_vector_type(4))) float f32x4;
typedef __attribute__((ext_vector_type(2))) float f32x2;
typedef __attribute__((ext_vector_type(4))) unsigned int u32x4;
typedef __attribute__((ext_vector_type(2))) unsigned int u32x2;

#define NTOK 4096
#define NT32 32   // 4096 / 128 t2-tiles

#if __has_builtin(__builtin_amdgcn_exp2f)
#define EXP2F __builtin_amdgcn_exp2f
#else
#define EXP2F exp2f
#endif

__device__ __forceinline__ f32x4 MFMA(bf16x8 a, bf16x8 b, f32x4 c) {
    return __builtin_amdgcn_mfma_f32_16x16x32_bf16(a, b, c, 0, 0, 0);
}

// packed f32->bf16 (D.lo = bf16(a), D.hi = bf16(b))
__device__ __forceinline__ uint32_t pk_bf16(float a, float b) {
    uint32_t d;
    asm("v_cvt_pk_bf16_f32 %0, %1, %2" : "=v"(d) : "v"(a), "v"(b));
    return d;
}

// truncation hi/lo split of 8 floats into two bf16x8 fragments
__device__ __forceinline__ void hilo_pack8(const float* v, bf16x8* h, bf16x8* l) {
    union { uint32_t u[4]; bf16x8 b; } H, L;
#pragma unroll
    for (int m = 0; m < 4; ++m) {
        const uint32_t ua = __float_as_uint(v[2*m]);
        const uint32_t ub = __float_as_uint(v[2*m+1]);
        const float la = v[2*m]   - __uint_as_float(ua & 0xffff0000u);
        const float lb = v[2*m+1] - __uint_as_float(ub & 0xffff0000u);
        H.u[m] = (ua >> 16) | (ub & 0xffff0000u);
        L.u[m] = (__float_as_uint(la) >> 16) | (__float_as_uint(lb) & 0xffff0000u);
    }
    *h = H.b; *l = L.b;
}

// ---------------------------------------------------------------------------
// k_qkv: QKV projection via MFMA (w,x hi/lo 3-term), then repack through LDS.
// (unchanged from round 4)
// ---------------------------------------------------------------------------
__global__ __launch_bounds__(256) void k_qkv(
    const float* __restrict__ x, const float* __restrict__ wqkv, const float* __restrict__ bqkv,
    u16* __restrict__ Qp, u16* __restrict__ Kp, u16* __restrict__ Vp)
{
    __shared__ float qt_lds[64 * 194];
    const int blk = blockIdx.x;
    const int b   = blk >> 6;
    const int tb  = (blk & 63) << 6;
    const int tid = threadIdx.x;
    const int lane = tid & 63;
    const int wv  = __builtin_amdgcn_readfirstlane(tid >> 6);
    const int r   = lane & 15;
    const int g   = lane >> 4;
    const int o0  = wv * 48;

    bf16x8 wh[3][2], wl[3][2];
#pragma unroll
    for (int oi = 0; oi < 3; ++oi)
#pragma unroll
        for (int ks = 0; ks < 2; ++ks) {
            const float* wp = wqkv + (size_t)(o0 + oi*16 + r) * 64 + ks*32 + g*8;
            float wv8[8];
            *(f32x4*)(wv8)     = *(const f32x4*)(wp);
            *(f32x4*)(wv8 + 4) = *(const f32x4*)(wp + 4);
            hilo_pack8(wv8, &wh[oi][ks], &wl[oi][ks]);
        }

    f32x4 acc[3][4];
#pragma unroll
    for (int oi = 0; oi < 3; ++oi)
#pragma unroll
        for (int tt = 0; tt < 4; ++tt) acc[oi][tt] = 0.f;

#pragma unroll
    for (int tt = 0; tt < 4; ++tt) {
        bf16x8 xh[2], xl[2];
#pragma unroll
        for (int ks = 0; ks < 2; ++ks) {
            float xv[8];
#pragma unroll
            for (int j = 0; j < 8; ++j)
                xv[j] = x[(size_t)(b*64 + ks*32 + g*8 + j) * NTOK + tb + tt*16 + r];
            hilo_pack8(xv, &xh[ks], &xl[ks]);
        }
#pragma unroll
        for (int oi = 0; oi < 3; ++oi) {
            f32x4 a = acc[oi][tt];
            a = MFMA(wh[oi][0], xh[0], a);
            a = MFMA(wh[oi][1], xh[1], a);
            a = MFMA(wl[oi][0], xh[0], a);
            a = MFMA(wl[oi][1], xh[1], a);
            a = MFMA(wh[oi][0], xl[0], a);
            a = MFMA(wh[oi][1], xl[1], a);
            acc[oi][tt] = a;
        }
    }

#pragma unroll
    for (int oi = 0; oi < 3; ++oi)
#pragma unroll
        for (int tt = 0; tt < 4; ++tt)
#pragma unroll
            for (int i = 0; i < 4; ++i)
                qt_lds[(tt*16 + r) * 194 + o0 + oi*16 + g*4 + i] = acc[oi][tt][i];
    __syncthreads();

    const float SC = 0.18033688011112042f;  // (1/8) * log2(e)

    {
        const int t = tid >> 2, c0 = (tid & 3) * 16;
        float v[16], bq[16];
#pragma unroll
        for (int m = 0; m < 8; ++m)
            *(f32x2*)(v + 2*m) = *(const f32x2*)&qt_lds[t*194 + c0 + 2*m];
#pragma unroll
        for (int m = 0; m < 4; ++m)
            *(f32x4*)(bq + 4*m) = *(const f32x4*)(bqkv + c0 + 4*m);
        u32x4 P0, P1;
#pragma unroll
        for (int m = 0; m < 4; ++m) {
            P0[m] = pk_bf16((v[2*m]   + bq[2*m]  ) * SC, (v[2*m+1] + bq[2*m+1]) * SC);
            P1[m] = pk_bf16((v[8+2*m] + bq[8+2*m]) * SC, (v[9+2*m] + bq[9+2*m]) * SC);
        }
        size_t base = ((size_t)(b * NTOK + tb + t)) * 64 + c0;
        *(u32x4*)(Qp + base)     = P0;
        *(u32x4*)(Qp + base + 8) = P1;
    }

#pragma unroll
    for (int uu = 0; uu < 2; ++uu) {
        const int u  = tid * 2 + uu;
        const int t  = u >> 3;
        const int ks = (u >> 2) & 1;
        const int gk = u & 3;
        const int cb0 = 64 + ks*32 + gk*8;
        float v[8];
#pragma unroll
        for (int m = 0; m < 4; ++m)
            *(f32x2*)(v + 2*m) = *(const f32x2*)&qt_lds[t*194 + cb0 + 2*m];
        u32x4 P;
#pragma unroll
        for (int m = 0; m < 4; ++m)
            P[m] = pk_bf16(v[2*m] + bqkv[cb0 + 2*m], v[2*m+1] + bqkv[cb0 + 2*m+1]);
        const int tg = tb + t;
        size_t kbase = (size_t)b * 262144 + ((size_t)(tg >> 4) * 2 + ks) * 512 + gk*128 + (t & 15) * 8;
        *(u32x4*)(Kp + kbase) = P;
    }

    {
        const int cb = (tid >> 4) & 3;
        const int r2 = tid & 15;
        const float bv = bqkv[128 + cb*16 + r2];
        const int T = (blk & 63) >> 1;
        const int halfb = blk & 1;
#pragma unroll
        for (int m = 0; m < 4; ++m) {
            const int tq = m * 4 + (tid >> 6);
            float v[4];
#pragma unroll
            for (int jj = 0; jj < 4; ++jj)
                v[jj] = qt_lds[(tq*4 + jj)*194 + 128 + cb*16 + r2] + bv;
            const int t = tq * 4;
            const int wtr = halfb*2 + (t >> 5);
            const int sti = (t >> 4) & 1;
            const int g2  = (t >> 2) & 3;
            u32x2 W;
            W[0] = pk_bf16(v[0], v[1]);
            W[1] = pk_bf16(v[2], v[3]);
            size_t vbase = (size_t)b * 262144 +
                           (((size_t)T * 4 + wtr) * 4 + cb) * 512 + (g2*16 + r2) * 8 + sti * 4;
            *(u32x2*)(Vp + vbase) = W;
        }
    }
}

// ---------------------------------------------------------------------------
// k_attn: flash attention, register-only barrier-free main loop.
// grid 1024 = 8 batches x 64 Q-tiles x 2 Q-halves; block 256 = 4 waves,
// each wave: 32 Q-rows x a 32-t2 slice of each 128-t2 tile.
// Small per-wave state (no K dbuf) -> VGPR<=128 -> 4 blocks/CU (16 waves).
// 4-way split-softmax merge + fused out-projection + residual in epilogue.
// ---------------------------------------------------------------------------
__global__ __launch_bounds__(256, 2) void k_attn(
    const u16* __restrict__ Qp, const u16* __restrict__ Kp, const u16* __restrict__ Vp,
    const float* __restrict__ wout, const float* __restrict__ bout,
    const float* __restrict__ x, float* __restrict__ out)
{
    __shared__ float marr[4][2][16];
    __shared__ float larr[4][2][16];
    __shared__ float otbuf[2][32 * 67];
    const int hw  = blockIdx.x;
    const int b   = hw & 7;        // batch -> XCD pinning
    const int rest = hw >> 3;      // 0..127
    const int qt  = rest >> 1;     // 0..63
    const int wq  = rest & 1;      // Q-half of the 64-row tile
    const int tid = threadIdx.x;
    const int lane = tid & 63;
    const int wt2 = tid >> 6;      // t2-slice 0..3
    const int r   = lane & 15;
    const int g   = lane >> 4;
    const int row0 = qt * 64 + wq * 32;

    // Q fragments (B operand), rows t1 = row0 + rt*16 + r
    bf16x8 qh[2][2];
#pragma unroll
    for (int rt = 0; rt < 2; ++rt) {
        const size_t qoff = ((size_t)(b * NTOK + row0 + rt*16 + r)) * 64 + g * 8;
        qh[rt][0] = *(const bf16x8*)(Qp + qoff);
        qh[rt][1] = *(const bf16x8*)(Qp + qoff + 32);
    }

    // running per-wave K/V pointers (advance 8192 elems = 16 KB per tile)
    const u16* kptr = Kp + (size_t)b * 262144 + ((size_t)(wt2 * 2) * 2) * 512 + lane * 8;
    const u16* vptr = Vp + (size_t)b * 262144 + ((size_t)wt2 * 4) * 512 + lane * 8;

    f32x4 oacc[2][4];
#pragma unroll
    for (int rt = 0; rt < 2; ++rt)
#pragma unroll
        for (int cb = 0; cb < 4; ++cb) oacc[rt][cb] = 0.f;
    float mrun[2] = {-1e30f, -1e30f};
    float lpart[2] = {0.f, 0.f};

    for (int T = 0; T < NT32; ++T) {
        // K fragments: sti*1024 + ks*512 element offsets
        bf16x8 kc[2][2];
#pragma unroll
        for (int sti = 0; sti < 2; ++sti)
#pragma unroll
            for (int ks = 0; ks < 2; ++ks)
                kc[sti][ks] = *(const bf16x8*)(kptr + sti*1024 + ks*512);
        // V fragments: cb*512 element offsets
        bf16x8 vf[4];
#pragma unroll
        for (int cb = 0; cb < 4; ++cb)
            vf[cb] = *(const bf16x8*)(vptr + cb*512);
        kptr += 8192;
        vptr += 8192;

        // QK^T
        f32x4 s[2][2];
        __builtin_amdgcn_s_setprio(1);
#pragma unroll
        for (int rt = 0; rt < 2; ++rt)
#pragma unroll
            for (int sti = 0; sti < 2; ++sti) {
                f32x4 a = 0.f;
                a = MFMA(kc[sti][0], qh[rt][0], a);
                a = MFMA(kc[sti][1], qh[rt][1], a);
                s[rt][sti] = a;
            }
        __builtin_amdgcn_s_setprio(0);

        // online softmax, deferred rescale (thr = 8 log2 units)
        float m8[2];
#pragma unroll
        for (int rt = 0; rt < 2; ++rt) {
            float a = fmaxf(fmaxf(s[rt][0][0], s[rt][0][1]), fmaxf(s[rt][0][2], s[rt][0][3]));
            float c = fmaxf(fmaxf(s[rt][1][0], s[rt][1][1]), fmaxf(s[rt][1][2], s[rt][1][3]));
            m8[rt] = fmaxf(a, c);
        }
        const bool need = (m8[0] > mrun[0] + 8.f) || (m8[1] > mrun[1] + 8.f);
        if (__any(need)) {
#pragma unroll
            for (int rt = 0; rt < 2; ++rt) {
                float mr = fmaxf(m8[rt], __shfl_xor(m8[rt], 16));
                mr = fmaxf(mr, __shfl_xor(mr, 32));
                const float mnew = fmaxf(mrun[rt], mr);
                const float corr = EXP2F(mrun[rt] - mnew);
                lpart[rt] *= corr;
                float c4[4];
#pragma unroll
                for (int i = 0; i < 4; ++i) c4[i] = __shfl(corr, g * 4 + i);
#pragma unroll
                for (int cb = 0; cb < 4; ++cb)
#pragma unroll
                    for (int i = 0; i < 4; ++i) oacc[rt][cb][i] *= c4[i];
                mrun[rt] = mnew;
            }
        }

        // P = exp2(S - m), PV
#pragma unroll
        for (int rt = 0; rt < 2; ++rt) {
            float p[8];
            float ls = 0.f;
#pragma unroll
            for (int sti = 0; sti < 2; ++sti)
#pragma unroll
                for (int i = 0; i < 4; ++i) {
                    const float pv = EXP2F(s[rt][sti][i] - mrun[rt]);
                    p[sti*4 + i] = pv; ls += pv;
                }
            lpart[rt] += ls;
            union { uint32_t u[4]; bf16x8 b; } PA;
#pragma unroll
            for (int m = 0; m < 4; ++m) PA.u[m] = pk_bf16(p[2*m], p[2*m+1]);
            __builtin_amdgcn_s_setprio(1);
#pragma unroll
            for (int cb = 0; cb < 4; ++cb)
                oacc[rt][cb] = MFMA(PA.b, vf[cb], oacc[rt][cb]);
            __builtin_amdgcn_s_setprio(0);
        }
    }

    // ---- epilogue: 4-way split-softmax merge across waves ----
    float lsum[2];
#pragma unroll
    for (int rt = 0; rt < 2; ++rt) {
        float v = lpart[rt];
        v += __shfl_xor(v, 16);
        v += __shfl_xor(v, 32);
        lsum[rt] = v;
    }
    if (lane < 16) {
#pragma unroll
        for (int rt = 0; rt < 2; ++rt) {
            marr[wt2][rt][lane] = mrun[rt];
            larr[wt2][rt][lane] = lsum[rt];
        }
    }
    __syncthreads();

    float w4[2][4];
#pragma unroll
    for (int rt = 0; rt < 2; ++rt) {
        const float m0 = marr[0][rt][r], m1 = marr[1][rt][r];
        const float m2 = marr[2][rt][r], m3 = marr[3][rt][r];
        const float mstar = fmaxf(fmaxf(m0, m1), fmaxf(m2, m3));
        const float lstar = larr[0][rt][r] * EXP2F(m0 - mstar)
                          + larr[1][rt][r] * EXP2F(m1 - mstar)
                          + larr[2][rt][r] * EXP2F(m2 - mstar)
                          + larr[3][rt][r] * EXP2F(m3 - mstar);
        const float wsc = EXP2F(mrun[rt] - mstar) / lstar;
#pragma unroll
        for (int i = 0; i < 4; ++i) w4[rt][i] = __shfl(wsc, g * 4 + i);
    }

    // accumulate O tile (32 rows x 64 cols): wt2 0/1 write bufs, 2/3 add
    if (wt2 < 2) {
        float* ob = otbuf[wt2];
#pragma unroll
        for (int rt = 0; rt < 2; ++rt)
#pragma unroll
            for (int cb = 0; cb < 4; ++cb)
#pragma unroll
                for (int i = 0; i < 4; ++i)
                    ob[(rt*16 + g*4 + i)*67 + cb*16 + r] = oacc[rt][cb][i] * w4[rt][i];
    }
    __syncthreads();
    if (wt2 >= 2) {
        float* ob = otbuf[wt2 - 2];
#pragma unroll
        for (int rt = 0; rt < 2; ++rt)
#pragma unroll
            for (int cb = 0; cb < 4; ++cb)
#pragma unroll
                for (int i = 0; i < 4; ++i)
                    ob[(rt*16 + g*4 + i)*67 + cb*16 + r] += oacc[rt][cb][i] * w4[rt][i];
    }
    __syncthreads();

    // ---- fused out-projection + bias + residual ----
    // wave wv: row-group rg = wt2&1 (16 rows), output-half ohf = wt2>>1
    const int rg  = wt2 & 1;
    const int ohf = wt2 >> 1;
    bf16x8 oh_[2], ol_[2];
#pragma unroll
    for (int ks = 0; ks < 2; ++ks) {
        float ov[8];
#pragma unroll
        for (int j = 0; j < 8; ++j) {
            const int idx = (rg*16 + r)*67 + ks*32 + g*8 + j;
            ov[j] = otbuf[0][idx] + otbuf[1][idx];
        }
        hilo_pack8(ov, &oh_[ks], &ol_[ks]);
    }
    f32x4 acc2[2];
#pragma unroll
    for (int ot = 0; ot < 2; ++ot) {
        bf16x8 wh2[2], wl2[2];
#pragma unroll
        for (int ks = 0; ks < 2; ++ks) {
            const float* wp = wout + (size_t)(ohf*32 + ot*16 + r) * 64 + ks*32 + g*8;
            float wv8[8];
            *(f32x4*)(wv8)     = *(const f32x4*)(wp);
            *(f32x4*)(wv8 + 4) = *(const f32x4*)(wp + 4);
            hilo_pack8(wv8, &wh2[ks], &wl2[ks]);
        }
        f32x4 a = 0.f;
        a = MFMA(wh2[0], oh_[0], a);
        a = MFMA(wh2[1], oh_[1], a);
        a = MFMA(wl2[0], oh_[0], a);
        a = MFMA(wl2[1], oh_[1], a);
        a = MFMA(wh2[0], ol_[0], a);
        a = MFMA(wh2[1], ol_[1], a);
        acc2[ot] = a;
    }
#pragma unroll
    for (int ot = 0; ot < 2; ++ot)
#pragma unroll
        for (int i = 0; i < 4; ++i) {
            const int oo = ohf*32 + ot*16 + g*4 + i;
            const size_t xi = ((size_t)(b*64 + oo)) * NTOK + row0 + rg*16 + r;
            out[xi] = acc2[ot][i] + bout[oo] + x[xi];
        }
}

extern "C" void kernel_launch(void* const* d_in, const int* in_sizes, int n_in,
                              void* d_out, int out_size, void* d_ws, size_t ws_size,
                              hipStream_t stream)
{
    (void)in_sizes; (void)n_in; (void)out_size; (void)ws_size;
    const float* x    = (const float*)d_in[0];
    const float* wqkv = (const float*)d_in[1];
    const float* bqkv = (const float*)d_in[2];
    const float* wout = (const float*)d_in[3];
    const float* bout = (const float*)d_in[4];
    float* out = (float*)d_out;

    char* ws = (char*)d_ws;
    const size_t MB = 1024 * 1024;
    u16* Qp = (u16*)(ws);
    u16* Kp = (u16*)(ws + 4 * MB);
    u16* Vp = (u16*)(ws + 8 * MB);

    k_qkv<<<512, 256, 0, stream>>>(x, wqkv, bqkv, Qp, Kp, Vp);
    k_attn<<<1024, 256, 0, stream>>>(Qp, Kp, Vp, wout, bout, x, out);
}